// Round 10
// baseline (197.519 us; speedup 1.0000x reference)
//
#include <hip/hip_runtime.h>
#include <math.h>

// ---------------------------------------------------------------------------
// QINRLayer: Linear+BN -> 10-qubit QNN (statevector sim) -> classical branch
// TWO launches only (R9 had 4; ~19us per kernel boundary dominated).
//   k_pre : per-feature BN stats WITHOUT materializing xq
//   k_qnn : xq recompute (4 samples/block) + gates + QNN + fused epilogue
//
// One wave per sample; 1024 complex amps in registers, PACKED as float2:
//   pair p holds j=2p (.x) and j=2p+1 (.y);  k = lane*16 + j.
//   wire w (0=MSB) <-> lane bit (5-w) for w<6; wires 6,7,8 <-> pair bits 2,1,0;
//   wire 9 <-> intra-pair half.
// All single-bit lane exchanges on the VALU path (R9): xor1/2 quad_perm DPP;
// xor4/8 row_shr+row_shl+sel; xor16/32 permlane*_swap. Only the ring's
// gray-code permutation remains on DS (128 bperm1/wave).
//
// Circuit algebra (all exact):
//   U0|0..0> product state -> direct init.   F_k = U_{k+1} * E fused layers.
//   CNOTs (0,1)..(4,5) -> one bpermute round (gray-code lane perm).
//   outs[1]=<X>, outs[2]=outs[3]=-<Y> direct from psi0 (H*H=I, rz3 diagonal).
//
// HARD-WON: do NOT set min-waves-per-EU in __launch_bounds__ (R2/R3 spill
// cascade: 40-48 VGPR + 1.7-3.3 GB scratch traffic). Plain (256) only.
// R6 lesson: epilogue fusion must use coalesced/L2-hot weight rows + full
// thread participation. R8 lesson: no same-address atomics across 1024 blocks.
// ---------------------------------------------------------------------------

typedef float v2f __attribute__((ext_vector_type(2)));
typedef unsigned uiv2 __attribute__((ext_vector_type(2)));

__device__ __forceinline__ float bperm1(int addr, float v){
  return __int_as_float(__builtin_amdgcn_ds_bpermute(addr, __float_as_int(v)));
}
__device__ __forceinline__ v2f bperm2(int addr, v2f v){
  v2f r; r.x = bperm1(addr, v.x); r.y = bperm1(addr, v.y); return r;
}
__device__ __forceinline__ v2f vs(float x){ return (v2f){x,x}; }

// ---- DPP / permlane cross-lane helpers (VALU pipe) --------------------------
template<int C>
__device__ __forceinline__ float dppf(float x){
  return __int_as_float(__builtin_amdgcn_update_dpp(0, __float_as_int(x),
                                                    C, 0xf, 0xf, true));
}
#define QP_X1 0xB1   // quad_perm [1,0,3,2]  == xor 1
#define QP_X2 0x4E   // quad_perm [2,3,0,1]  == xor 2

__device__ __forceinline__ float xor1f(float x, int /*lane*/){ return dppf<QP_X1>(x); }
__device__ __forceinline__ float xor2f(float x, int /*lane*/){ return dppf<QP_X2>(x); }

template<int N>   // N = 4 or 8 (in-row)
__device__ __forceinline__ float xorshf(float x, int lane){
  float a = dppf<0x110+N>(x);   // row_shr:N
  float b = dppf<0x100+N>(x);   // row_shl:N
  return (lane & N) ? a : b;
}
__device__ __forceinline__ float xor4f(float x, int lane){ return xorshf<4>(x,lane); }
__device__ __forceinline__ float xor8f(float x, int lane){ return xorshf<8>(x,lane); }

#if __has_builtin(__builtin_amdgcn_permlane16_swap) && __has_builtin(__builtin_amdgcn_permlane32_swap)
__device__ __forceinline__ float xor16f(float x, int lane){
  uiv2 r = __builtin_amdgcn_permlane16_swap(__float_as_uint(x), __float_as_uint(x),
                                            false, false);
  return __uint_as_float((lane & 16) ? r.x : r.y);
}
__device__ __forceinline__ float xor32f(float x, int lane){
  uiv2 r = __builtin_amdgcn_permlane32_swap(__float_as_uint(x), __float_as_uint(x),
                                            false, false);
  return __uint_as_float((lane & 32) ? r.x : r.y);
}
#else
__device__ __forceinline__ float xor16f(float x, int lane){ return bperm1((lane^16)<<2, x); }
__device__ __forceinline__ float xor32f(float x, int lane){ return bperm1((lane^32)<<2, x); }
#endif

#define DEF_XORV(NAME, F1) \
__device__ __forceinline__ v2f NAME(v2f v, int lane){ \
  v2f r; r.x = F1(v.x,lane); r.y = F1(v.y,lane); return r; }
DEF_XORV(xor1v,  xor1f)
DEF_XORV(xor2v,  xor2f)
DEF_XORV(xor4v,  xor4f)
DEF_XORV(xor8v,  xor8f)
DEF_XORV(xor16v, xor16f)
DEF_XORV(xor32v, xor32f)

// full wave64 sum; valid in lane 63 only
__device__ __forceinline__ float dsum(float x){
  x += dppf<0x111>(x);   // row_shr:1
  x += dppf<0x112>(x);   // row_shr:2
  x += dppf<0x114>(x);   // row_shr:4
  x += dppf<0x118>(x);   // row_shr:8
  x += dppf<0x142>(x);   // row_bcast:15
  x += dppf<0x143>(x);   // row_bcast:31
  return x;
}

// ---------------- gate primitives (packed state) ----------------------------

#define DEF_GCROSS(NAME, PFN) \
__device__ __forceinline__ void NAME(v2f (&R)[8], v2f (&I)[8], int lane, bool hi, \
                                     const float* g){ \
  const float gar = hi ? g[6] : g[0], gai = hi ? g[7] : g[1]; \
  const float gbr = hi ? g[4] : g[2], gbi = hi ? g[5] : g[3]; \
  const v2f A=vs(gar), B=vs(gai), C=vs(gbr), D=vs(gbi); \
  _Pragma("unroll") \
  for (int p=0;p<8;++p){ \
    v2f PR = PFN(R[p],lane); \
    v2f PI = PFN(I[p],lane); \
    v2f nr = A*R[p] - B*I[p] + C*PR - D*PI; \
    v2f ni = A*I[p] + B*R[p] + C*PI + D*PR; \
    R[p]=nr; I[p]=ni; } \
}
DEF_GCROSS(g_cross_x32, xor32v)
DEF_GCROSS(g_cross_x16, xor16v)
DEF_GCROSS(g_cross_x8,  xor8v)
DEF_GCROSS(g_cross_x4,  xor4v)
DEF_GCROSS(g_cross_x2,  xor2v)
DEF_GCROSS(g_cross_x1,  xor1v)

// local wires 6,7,8 -> pair masks 4,2,1
template<int PM>
__device__ __forceinline__ void g_localp(v2f (&R)[8], v2f (&I)[8], const float* g)
{
  const v2f g00r=vs(g[0]), g00i=vs(g[1]), g01r=vs(g[2]), g01i=vs(g[3]);
  const v2f g10r=vs(g[4]), g10i=vs(g[5]), g11r=vs(g[6]), g11i=vs(g[7]);
#pragma unroll
  for (int p=0;p<8;++p) if (!(p&PM)) {
    const int q = p|PM;
    v2f r0=R[p], i0=I[p], r1=R[q], i1=I[q];
    R[p] = g00r*r0 - g00i*i0 + g01r*r1 - g01i*i1;
    I[p] = g00r*i0 + g00i*r0 + g01r*i1 + g01i*r1;
    R[q] = g10r*r0 - g10i*i0 + g11r*r1 - g11i*i1;
    I[q] = g10r*i0 + g10i*r0 + g11r*i1 + g11i*r1;
  }
}

// wire 9: intra-pair
__device__ __forceinline__ void g_local9(v2f (&R)[8], v2f (&I)[8], const float* g)
{
  const v2f Gr0 = (v2f){g[0], g[4]};
  const v2f Gi0 = (v2f){g[1], g[5]};
  const v2f Gr1 = (v2f){g[2], g[6]};
  const v2f Gi1 = (v2f){g[3], g[7]};
#pragma unroll
  for (int p=0;p<8;++p) {
    v2f Rx = vs(R[p].x), Ix = vs(I[p].x);
    v2f Ry = vs(R[p].y), Iy = vs(I[p].y);
    R[p] = Gr0*Rx - Gi0*Ix + Gr1*Ry - Gi1*Iy;
    I[p] = Gr0*Ix + Gi0*Rx + Gr1*Iy + Gi1*Ry;
  }
}

// ---------------- CNOT ring --------------------------------------------------
__device__ __forceinline__ void cnot_ring(v2f (&R)[8], v2f (&I)[8],
                                          int addrg, int lane, bool c5)
{
#pragma unroll
  for (int p=0;p<8;++p) R[p] = bperm2(addrg, R[p]);
#pragma unroll
  for (int p=0;p<8;++p) I[p] = bperm2(addrg, I[p]);
#pragma unroll
  for (int p=0;p<4;++p) {
    v2f a=R[p], b=R[p|4];
    R[p]   = c5 ? b : a;
    R[p|4] = c5 ? a : b;
    v2f ai=I[p], bi=I[p|4];
    I[p]   = c5 ? bi : ai;
    I[p|4] = c5 ? ai : bi;
  }
#pragma unroll
  for (int p=0;p<8;++p) if ((p&4)&&!(p&2)) {
    const int q=p|2;
    v2f t=R[p]; R[p]=R[q]; R[q]=t;
    t=I[p]; I[p]=I[q]; I[q]=t;
  }
#pragma unroll
  for (int p=0;p<8;++p) if ((p&2)&&!(p&1)) {
    const int q=p|1;
    v2f t=R[p]; R[p]=R[q]; R[q]=t;
    t=I[p]; I[p]=I[q]; I[q]=t;
  }
#pragma unroll
  for (int p=1;p<8;p+=2) {
    R[p] = __builtin_shufflevector(R[p],R[p],1,0);
    I[p] = __builtin_shufflevector(I[p],I[p],1,0);
  }
#pragma unroll
  for (int p=0;p<8;++p) {
    R[p].y = xor32f(R[p].y, lane);
    I[p].y = xor32f(I[p].y, lane);
  }
}

// ---------------- k_pre: BN stats without materializing xq ------------------
// grid 40 (one block per feature), block 1024
__global__ __launch_bounds__(1024) void k_pre(const float* __restrict__ x,
    const float* __restrict__ qw, const float* __restrict__ qb,
    const float* __restrict__ gamma, const float* __restrict__ beta,
    float* __restrict__ bn_a, float* __restrict__ bn_c)
{
  const int f = blockIdx.x, t = threadIdx.x;
  __shared__ float wf[40];
  __shared__ float a1[16], a2[16];
  if (t < 40) wf[t] = qw[f*40 + t];
  __syncthreads();
  const float bf = qb[f];
  float s1 = 0.f, s2 = 0.f;
  for (int s = t; s < 8192; s += 1024) {
    const float4* xr = (const float4*)(x + s*40);
    float d = bf;
#pragma unroll
    for (int q = 0; q < 10; ++q) {
      float4 v = xr[q];
      d = fmaf(v.x, wf[4*q+0], d);
      d = fmaf(v.y, wf[4*q+1], d);
      d = fmaf(v.z, wf[4*q+2], d);
      d = fmaf(v.w, wf[4*q+3], d);
    }
    s1 += d; s2 = fmaf(d, d, s2);
  }
  s1 = dsum(s1); s2 = dsum(s2);
  const int lane = t & 63, wid = t >> 6;
  if (lane == 63) { a1[wid] = s1; a2[wid] = s2; }
  __syncthreads();
  if (t == 0) {
    float t1 = 0.f, t2 = 0.f;
#pragma unroll
    for (int i = 0; i < 16; ++i) { t1 += a1[i]; t2 += a2[i]; }
    float mu  = t1 * (1.f/8192.f);
    float var = t2 * (1.f/8192.f) - mu*mu;
    float a = gamma[f] * rsqrtf(var + 1e-5f);
    bn_a[f] = a; bn_c[f] = beta[f] - mu*a;
  }
}

// ---------------- k_qnn: everything else ------------------------------------

#define GEN10(PTR) \
  g_cross_x32(R,I,lane,h0,(PTR)+0);  g_cross_x16(R,I,lane,h1,(PTR)+8);  \
  g_cross_x8 (R,I,lane,h2,(PTR)+16); g_cross_x4 (R,I,lane,h3,(PTR)+24); \
  g_cross_x2 (R,I,lane,h4,(PTR)+32); g_cross_x1 (R,I,lane,h5,(PTR)+40); \
  g_localp<4>(R,I,(PTR)+48);   g_localp<2>(R,I,(PTR)+56);   \
  g_localp<1>(R,I,(PTR)+64);   g_local9(R,I,(PTR)+72);

// Plain launch bounds — min-waves arg causes spill cascade (see header).
__global__ __launch_bounds__(256) void k_qnn(const float* __restrict__ x,
    const float* __restrict__ qlin_w, const float* __restrict__ qlin_b,
    const float* __restrict__ bn_a, const float* __restrict__ bn_c,
    const float* __restrict__ rz1, const float* __restrict__ ry1,
    const float* __restrict__ rz2,
    const float* __restrict__ clin_w, const float* __restrict__ clin_b,
    const float* __restrict__ lin_w, const float* __restrict__ lin_b,
    float* __restrict__ out)
{
  const int tix  = threadIdx.x;
  const int lane = tix & 63;
  const int wv   = tix >> 6;
  const int s    = blockIdx.x*4 + wv;

  __shared__ float Gbuf[40][8];     // fused param gates Rz2*Ry1*Rz1
  __shared__ float Ebuf[4][10][8];
  __shared__ float Fbuf[4][3][10][8];
  __shared__ float xs [4][40];      // raw x rows (reused by epilogue)
  __shared__ float xqs[4][40];      // xq = x@qlin^T+b for the 4 samples
  __shared__ float x1s[4][40];      // QNN outputs
  __shared__ float x2s[4][40];      // relu branch

  // ---- stage x rows (coalesced) + gate consts in parallel
  if (tix < 160) xs[tix/40][tix%40] = x[blockIdx.x*160 + tix];
  {
    const int gi = tix - 160;
    if (gi >= 0 && gi < 40) {
      float g = rz1[gi], ay = ry1[gi], bz = rz2[gi];
      float ca, sa, cp, sp, cm, sm;
      sincosf(0.5f*ay, &sa, &ca);
      sincosf(0.5f*(bz+g), &sp, &cp);
      sincosf(0.5f*(bz-g), &sm, &cm);
      float* G = &Gbuf[gi][0];
      G[0]= ca*cp; G[1]=-ca*sp;
      G[2]=-sa*cm; G[3]= sa*sm;
      G[4]= sa*cm; G[5]= sa*sm;
      G[6]= ca*cp; G[7]= ca*sp;
    }
  }
  __syncthreads();

  // ---- xq for our 4 samples (weights L2-hot, aligned float4 rows)
  if (tix < 160) {
    const int sl = tix/40, f = tix - sl*40;
    const float4* qw = (const float4*)(qlin_w + f*40);
    float acc = qlin_b[f];
#pragma unroll
    for (int q = 0; q < 10; ++q) {
      float4 v = qw[q];
      acc = fmaf(v.x, xs[sl][4*q+0], acc);
      acc = fmaf(v.y, xs[sl][4*q+1], acc);
      acc = fmaf(v.z, xs[sl][4*q+2], acc);
      acc = fmaf(v.w, xs[sl][4*q+3], acc);
    }
    xqs[sl][f] = acc;
  }
  __syncthreads();

  // ---- per-sample fused encoder matrix per wire: Rx(f3) Rz(f2) Ry(f1) Rx(f0)
  if (lane < 10) {
    const int i = lane;
    const int f = 4*i;
    float h0 = 0.5f * fmaf(xqs[wv][f+0], bn_a[f+0], bn_c[f+0]);
    float h1 = 0.5f * fmaf(xqs[wv][f+1], bn_a[f+1], bn_c[f+1]);
    float h2 = 0.5f * fmaf(xqs[wv][f+2], bn_a[f+2], bn_c[f+2]);
    float h3 = 0.5f * fmaf(xqs[wv][f+3], bn_a[f+3], bn_c[f+3]);
    float c0,s0,c1,s1,c2,s2,c3,s3;
    sincosf(h0,&s0,&c0); sincosf(h1,&s1,&c1);
    sincosf(h2,&s2,&c2); sincosf(h3,&s3,&c3);
    float A00r=c1*c0, A00i= s1*s0;
    float A01r=-s1*c0, A01i=-c1*s0;
    float A10r= s1*c0, A10i=-c1*s0;
    float A11r= c1*c0, A11i=-s1*s0;
    float B00r = A00r*c2 + A00i*s2, B00i = A00i*c2 - A00r*s2;
    float B01r = A01r*c2 + A01i*s2, B01i = A01i*c2 - A01r*s2;
    float B10r = A10r*c2 - A10i*s2, B10i = A10i*c2 + A10r*s2;
    float B11r = A11r*c2 - A11i*s2, B11i = A11i*c2 + A11r*s2;
    float* e = &Ebuf[wv][i][0];
    e[0] = c3*B00r + s3*B10i;  e[1] = c3*B00i - s3*B10r;
    e[2] = c3*B01r + s3*B11i;  e[3] = c3*B01i - s3*B11r;
    e[4] = c3*B10r + s3*B00i;  e[5] = c3*B10i - s3*B00r;
    e[6] = c3*B11r + s3*B01i;  e[7] = c3*B11i - s3*B01r;
  }

  // ---- fused F_k = U_{k+1} * E (same wave reads its own Ebuf rows)
  if (lane < 30) {
    const int k = lane/10, i = lane - k*10;
    const float* U = &Gbuf[(k+1)*10 + i][0];
    const float* E = &Ebuf[wv][i][0];
    float u00r=U[0],u00i=U[1],u01r=U[2],u01i=U[3],u10r=U[4],u10i=U[5],u11r=U[6],u11i=U[7];
    float e00r=E[0],e00i=E[1],e01r=E[2],e01i=E[3],e10r=E[4],e10i=E[5],e11r=E[6],e11i=E[7];
    float* F = &Fbuf[wv][k][i][0];
    F[0] = u00r*e00r - u00i*e00i + u01r*e10r - u01i*e10i;
    F[1] = u00r*e00i + u00i*e00r + u01r*e10i + u01i*e10r;
    F[2] = u00r*e01r - u00i*e01i + u01r*e11r - u01i*e11i;
    F[3] = u00r*e01i + u00i*e01r + u01r*e11i + u01i*e11r;
    F[4] = u10r*e00r - u10i*e00i + u11r*e10r - u11i*e10i;
    F[5] = u10r*e00i + u10i*e00r + u11r*e10i + u11i*e10r;
    F[6] = u10r*e01r - u10i*e01i + u11r*e11r - u11i*e11i;
    F[7] = u10r*e01i + u10i*e01r + u11r*e11i + u11i*e11r;
  }

  const bool h0 = (lane & 32) != 0;
  const bool h1 = (lane & 16) != 0;
  const bool h2 = (lane &  8) != 0;
  const bool h3 = (lane &  4) != 0;
  const bool h4 = (lane &  2) != 0;
  const bool h5 = (lane &  1) != 0;
  const int addrg = (lane ^ (lane >> 1)) << 2;

  // ---- init: state = U0 |0..0>  (product state, column 0 per wire)
  v2f R[8], I[8];
  {
    float cr = 1.f, ci = 0.f;
#pragma unroll
    for (int w=0; w<6; ++w) {
      const float g0r = Gbuf[w][0], g0i = Gbuf[w][1];
      const float g1r = Gbuf[w][4], g1i = Gbuf[w][5];
      const bool bset = (lane >> (5-w)) & 1;
      const float ar = bset ? g1r : g0r, ai = bset ? g1i : g0i;
      const float tr = cr*ar - ci*ai, ti = cr*ai + ci*ar;
      cr = tr; ci = ti;
    }
    float p67r[4], p67i[4], p89r[4], p89i[4];
#pragma unroll
    for (int b6=0;b6<2;++b6)
#pragma unroll
      for (int b7=0;b7<2;++b7) {
        const float x6r = Gbuf[6][4*b6], x6i = Gbuf[6][4*b6+1];
        const float x7r = Gbuf[7][4*b7], x7i = Gbuf[7][4*b7+1];
        p67r[b6*2+b7] = x6r*x7r - x6i*x7i;
        p67i[b6*2+b7] = x6r*x7i + x6i*x7r;
      }
#pragma unroll
    for (int b8=0;b8<2;++b8)
#pragma unroll
      for (int b9=0;b9<2;++b9) {
        const float x8r = Gbuf[8][4*b8], x8i = Gbuf[8][4*b8+1];
        const float x9r = Gbuf[9][4*b9], x9i = Gbuf[9][4*b9+1];
        p89r[b8*2+b9] = x8r*x9r - x8i*x9i;
        p89i[b8*2+b9] = x8r*x9i + x8i*x9r;
      }
#pragma unroll
    for (int m=0;m<4;++m) {
      const float tr = p67r[m]*cr - p67i[m]*ci;
      const float ti = p67r[m]*ci + p67i[m]*cr;
      p67r[m]=tr; p67i[m]=ti;
    }
#pragma unroll
    for (int p=0;p<8;++p) {
      const int hi = p>>1, b8 = p&1;
      const v2f Pr = (v2f){p89r[2*b8], p89r[2*b8+1]};
      const v2f Pi = (v2f){p89i[2*b8], p89i[2*b8+1]};
      R[p] = vs(p67r[hi])*Pr - vs(p67i[hi])*Pi;
      I[p] = vs(p67r[hi])*Pi + vs(p67i[hi])*Pr;
    }
  }

  // ---- main circuit: 4 rings interleaved with 3 fused layers
  cnot_ring(R,I,addrg,lane,h5);
  { const float* F = &Fbuf[wv][0][0][0]; GEN10(F) }
  cnot_ring(R,I,addrg,lane,h5);
  { const float* F = &Fbuf[wv][1][0][0]; GEN10(F) }
  cnot_ring(R,I,addrg,lane,h5);
  { const float* F = &Fbuf[wv][2][0][0]; GEN10(F) }
  cnot_ring(R,I,addrg,lane,h5);

  float* dst = &x1s[wv][0];

  // ---- outs[0]: <Z_w> from probabilities
  {
    v2f pv[8];
#pragma unroll
    for (int p=0;p<8;++p) pv[p] = R[p]*R[p] + I[p]*I[p];
    v2f T8 = (pv[0]-pv[1]) + (pv[2]-pv[3]) + (pv[4]-pv[5]) + (pv[6]-pv[7]);
    v2f aa[4];
#pragma unroll
    for (int m=0;m<4;++m) aa[m] = pv[2*m] + pv[2*m+1];
    v2f T7 = (aa[0]-aa[1]) + (aa[2]-aa[3]);
    v2f T6 = (aa[0]+aa[1]) - (aa[2]+aa[3]);
    v2f S  = (aa[0]+aa[1]) + (aa[2]+aa[3]);
    float q8 = T8.x + T8.y;
    float q7 = T7.x + T7.y;
    float q6 = T6.x + T6.y;
    float q9 = S.x - S.y;
    float P  = S.x + S.y;

    float v = P;
    { float pt = xor1f (v,lane); v = h5 ? (pt - v) : (pt + v); }
    { float pt = xor2f (v,lane); v = h4 ? (pt - v) : (pt + v); }
    { float pt = xor4f (v,lane); v = h3 ? (pt - v) : (pt + v); }
    { float pt = xor8f (v,lane); v = h2 ? (pt - v) : (pt + v); }
    { float pt = xor16f(v,lane); v = h1 ? (pt - v) : (pt + v); }
    { float pt = xor32f(v,lane); v = h0 ? (pt - v) : (pt + v); }

    q6 = dsum(q6); q7 = dsum(q7); q8 = dsum(q8); q9 = dsum(q9);

    if (lane==32) dst[0]=v;
    if (lane==16) dst[1]=v;
    if (lane== 8) dst[2]=v;
    if (lane== 4) dst[3]=v;
    if (lane== 2) dst[4]=v;
    if (lane== 1) dst[5]=v;
    if (lane==63){ dst[6]=q6; dst[7]=q7; dst[8]=q8; dst[9]=q9; }
  }

  // ---- outs[1]=<X>, outs[2]=outs[3]=-<Y>, direct from psi0
#define XYC(PFN,HW,W) { \
    v2f U=vs(0.f), V=vs(0.f); \
    _Pragma("unroll") \
    for (int p=0;p<8;++p) { \
      v2f PR = PFN(R[p],lane); \
      v2f PI = PFN(I[p],lane); \
      U += R[p]*PR + I[p]*PI; \
      V += I[p]*PR - R[p]*PI; \
    } \
    float u = U.x + U.y; \
    float vv = V.x + V.y; \
    vv = (HW) ? vv : -vv; \
    u = dsum(u); vv = dsum(vv); \
    if (lane==63){ dst[10+(W)]=u; dst[20+(W)]=vv; dst[30+(W)]=vv; } \
  }
  XYC(xor32v,h0,0) XYC(xor16v,h1,1) XYC(xor8v,h2,2)
  XYC(xor4v ,h3,3) XYC(xor2v ,h4,4) XYC(xor1v,h5,5)
#undef XYC

#define XYL(PM,W) { \
    v2f U=vs(0.f), V=vs(0.f); \
    _Pragma("unroll") \
    for (int p=0;p<8;++p) if (!(p&(PM))) { \
      const int q=p|(PM); \
      U += R[p]*R[q] + I[p]*I[q]; \
      V += I[p]*R[q] - R[p]*I[q]; \
    } \
    float u = U.x + U.y; \
    float vv = V.x + V.y; \
    u = dsum(u); vv = dsum(vv); \
    if (lane==63){ dst[10+(W)]=2.f*u; float y=-2.f*vv; dst[20+(W)]=y; dst[30+(W)]=y; } \
  }
  XYL(4,6) XYL(2,7) XYL(1,8)
#undef XYL

  {
    float u=0.f, vv=0.f;
#pragma unroll
    for (int p=0;p<8;++p) {
      u  = fmaf(R[p].x, R[p].y, u);  u  = fmaf(I[p].x, I[p].y, u);
      vv = fmaf(I[p].x, R[p].y, vv); vv = fmaf(-R[p].x, I[p].y, vv);
    }
    u = dsum(u); vv = dsum(vv);
    if (lane==63){ dst[19]=2.f*u; float y=-2.f*vv; dst[29]=y; dst[39]=y; }
  }

  // ---- fused epilogue: x2 = relu(x@clin^T+b); out = [x1,x2]@lin^T + b
  __syncthreads();
  if (tix < 160) {
    const int sl = tix/40, f = tix - sl*40;
    const float4* cw = (const float4*)(clin_w + f*40);
    float acc = clin_b[f];
#pragma unroll
    for (int q = 0; q < 10; ++q) {
      float4 v = cw[q];
      acc = fmaf(v.x, xs[sl][4*q+0], acc);
      acc = fmaf(v.y, xs[sl][4*q+1], acc);
      acc = fmaf(v.z, xs[sl][4*q+2], acc);
      acc = fmaf(v.w, xs[sl][4*q+3], acc);
    }
    x2s[sl][f] = fmaxf(acc, 0.f);
  }
  __syncthreads();
  if (tix < 160) {
    const int sl = tix/40, f = tix - sl*40;
    const float4* lw = (const float4*)(lin_w + f*80);
    float o = lin_b[f];
#pragma unroll
    for (int q = 0; q < 10; ++q) {
      float4 v = lw[q];
      o = fmaf(v.x, x1s[sl][4*q+0], o);
      o = fmaf(v.y, x1s[sl][4*q+1], o);
      o = fmaf(v.z, x1s[sl][4*q+2], o);
      o = fmaf(v.w, x1s[sl][4*q+3], o);
    }
#pragma unroll
    for (int q = 10; q < 20; ++q) {
      float4 v = lw[q];
      o = fmaf(v.x, x2s[sl][4*(q-10)+0], o);
      o = fmaf(v.y, x2s[sl][4*(q-10)+1], o);
      o = fmaf(v.z, x2s[sl][4*(q-10)+2], o);
      o = fmaf(v.w, x2s[sl][4*(q-10)+3], o);
    }
    out[blockIdx.x*160 + tix] = o;
  }
}

// ---------------- launch ---------------------------------------------------
extern "C" void kernel_launch(void* const* d_in, const int* in_sizes, int n_in,
                              void* d_out, int out_size, void* d_ws, size_t ws_size,
                              hipStream_t stream)
{
  const float* x      = (const float*)d_in[0];
  const float* qlin_w = (const float*)d_in[1];
  const float* qlin_b = (const float*)d_in[2];
  const float* bn_g   = (const float*)d_in[3];
  const float* bn_b   = (const float*)d_in[4];
  const float* clin_w = (const float*)d_in[5];
  const float* clin_b = (const float*)d_in[6];
  const float* lin_w  = (const float*)d_in[7];
  const float* lin_b  = (const float*)d_in[8];
  const float* rz1    = (const float*)d_in[9];
  const float* ry1    = (const float*)d_in[10];
  const float* rz2    = (const float*)d_in[11];

  float* ws   = (float*)d_ws;
  float* bn_a = ws;        // 40
  float* bn_c = ws + 40;   // 40
  float* out  = (float*)d_out;

  hipLaunchKernelGGL(k_pre, dim3(40),   dim3(1024), 0, stream,
                     x, qlin_w, qlin_b, bn_g, bn_b, bn_a, bn_c);
  hipLaunchKernelGGL(k_qnn, dim3(2048), dim3(256),  0, stream,
                     x, qlin_w, qlin_b, bn_a, bn_c, rz1, ry1, rz2,
                     clin_w, clin_b, lin_w, lin_b, out);
}

// Round 11
// 176.967 us; speedup vs baseline: 1.1161x; 1.1161x over previous
//
#include <hip/hip_runtime.h>
#include <math.h>

// ---------------------------------------------------------------------------
// QINRLayer: Linear+BN -> 10-qubit QNN (statevector sim) -> classical branch
// TWO launches:
//   k_pre : BN partial stats, 320 blocks (40 features x 8 sample-slices)
//           -- R10 lesson: grid-40 k_pre left 216 CUs idle and cost ~30us.
//   k_qnn : partial-reduce + xq recompute (4 samples/block) + gates + QNN
//           + fused epilogue  (R10 body, 104us, VALU-bound 82%)
//
// One wave per sample; 1024 complex amps in registers, PACKED as float2:
//   pair p holds j=2p (.x) and j=2p+1 (.y);  k = lane*16 + j.
//   wire w (0=MSB) <-> lane bit (5-w) for w<6; wires 6,7,8 <-> pair bits 2,1,0;
//   wire 9 <-> intra-pair half.
// All single-bit lane exchanges on the VALU path (R9): xor1/2 quad_perm DPP;
// xor4/8 row_shr+row_shl+sel; xor16/32 permlane*_swap. Only the ring's
// gray-code permutation remains on DS (128 bperm1/wave).
//
// Circuit algebra (all exact):
//   U0|0..0> product state -> direct init.   F_k = U_{k+1} * E fused layers.
//   CNOTs (0,1)..(4,5) -> one bpermute round (gray-code lane perm).
//   outs[1]=<X>, outs[2]=outs[3]=-<Y> direct from psi0 (H*H=I, rz3 diagonal).
//
// HARD-WON: do NOT set min-waves-per-EU in __launch_bounds__ (R2/R3 spill
// cascade). R8: no same-address atomics across 1024 blocks. R6: epilogue
// fusion needs coalesced weight rows + full participation (R10 version ok).
// ---------------------------------------------------------------------------

typedef float v2f __attribute__((ext_vector_type(2)));
typedef unsigned uiv2 __attribute__((ext_vector_type(2)));

__device__ __forceinline__ float bperm1(int addr, float v){
  return __int_as_float(__builtin_amdgcn_ds_bpermute(addr, __float_as_int(v)));
}
__device__ __forceinline__ v2f bperm2(int addr, v2f v){
  v2f r; r.x = bperm1(addr, v.x); r.y = bperm1(addr, v.y); return r;
}
__device__ __forceinline__ v2f vs(float x){ return (v2f){x,x}; }

// ---- DPP / permlane cross-lane helpers (VALU pipe) --------------------------
template<int C>
__device__ __forceinline__ float dppf(float x){
  return __int_as_float(__builtin_amdgcn_update_dpp(0, __float_as_int(x),
                                                    C, 0xf, 0xf, true));
}
#define QP_X1 0xB1   // quad_perm [1,0,3,2]  == xor 1
#define QP_X2 0x4E   // quad_perm [2,3,0,1]  == xor 2

__device__ __forceinline__ float xor1f(float x, int /*lane*/){ return dppf<QP_X1>(x); }
__device__ __forceinline__ float xor2f(float x, int /*lane*/){ return dppf<QP_X2>(x); }

template<int N>   // N = 4 or 8 (in-row)
__device__ __forceinline__ float xorshf(float x, int lane){
  float a = dppf<0x110+N>(x);   // row_shr:N
  float b = dppf<0x100+N>(x);   // row_shl:N
  return (lane & N) ? a : b;
}
__device__ __forceinline__ float xor4f(float x, int lane){ return xorshf<4>(x,lane); }
__device__ __forceinline__ float xor8f(float x, int lane){ return xorshf<8>(x,lane); }

#if __has_builtin(__builtin_amdgcn_permlane16_swap) && __has_builtin(__builtin_amdgcn_permlane32_swap)
__device__ __forceinline__ float xor16f(float x, int lane){
  uiv2 r = __builtin_amdgcn_permlane16_swap(__float_as_uint(x), __float_as_uint(x),
                                            false, false);
  return __uint_as_float((lane & 16) ? r.x : r.y);
}
__device__ __forceinline__ float xor32f(float x, int lane){
  uiv2 r = __builtin_amdgcn_permlane32_swap(__float_as_uint(x), __float_as_uint(x),
                                            false, false);
  return __uint_as_float((lane & 32) ? r.x : r.y);
}
#else
__device__ __forceinline__ float xor16f(float x, int lane){ return bperm1((lane^16)<<2, x); }
__device__ __forceinline__ float xor32f(float x, int lane){ return bperm1((lane^32)<<2, x); }
#endif

#define DEF_XORV(NAME, F1) \
__device__ __forceinline__ v2f NAME(v2f v, int lane){ \
  v2f r; r.x = F1(v.x,lane); r.y = F1(v.y,lane); return r; }
DEF_XORV(xor1v,  xor1f)
DEF_XORV(xor2v,  xor2f)
DEF_XORV(xor4v,  xor4f)
DEF_XORV(xor8v,  xor8f)
DEF_XORV(xor16v, xor16f)
DEF_XORV(xor32v, xor32f)

// full wave64 sum; valid in lane 63 only
__device__ __forceinline__ float dsum(float x){
  x += dppf<0x111>(x);   // row_shr:1
  x += dppf<0x112>(x);   // row_shr:2
  x += dppf<0x114>(x);   // row_shr:4
  x += dppf<0x118>(x);   // row_shr:8
  x += dppf<0x142>(x);   // row_bcast:15
  x += dppf<0x143>(x);   // row_bcast:31
  return x;
}

// ---------------- gate primitives (packed state) ----------------------------

#define DEF_GCROSS(NAME, PFN) \
__device__ __forceinline__ void NAME(v2f (&R)[8], v2f (&I)[8], int lane, bool hi, \
                                     const float* g){ \
  const float gar = hi ? g[6] : g[0], gai = hi ? g[7] : g[1]; \
  const float gbr = hi ? g[4] : g[2], gbi = hi ? g[5] : g[3]; \
  const v2f A=vs(gar), B=vs(gai), C=vs(gbr), D=vs(gbi); \
  _Pragma("unroll") \
  for (int p=0;p<8;++p){ \
    v2f PR = PFN(R[p],lane); \
    v2f PI = PFN(I[p],lane); \
    v2f nr = A*R[p] - B*I[p] + C*PR - D*PI; \
    v2f ni = A*I[p] + B*R[p] + C*PI + D*PR; \
    R[p]=nr; I[p]=ni; } \
}
DEF_GCROSS(g_cross_x32, xor32v)
DEF_GCROSS(g_cross_x16, xor16v)
DEF_GCROSS(g_cross_x8,  xor8v)
DEF_GCROSS(g_cross_x4,  xor4v)
DEF_GCROSS(g_cross_x2,  xor2v)
DEF_GCROSS(g_cross_x1,  xor1v)

// local wires 6,7,8 -> pair masks 4,2,1
template<int PM>
__device__ __forceinline__ void g_localp(v2f (&R)[8], v2f (&I)[8], const float* g)
{
  const v2f g00r=vs(g[0]), g00i=vs(g[1]), g01r=vs(g[2]), g01i=vs(g[3]);
  const v2f g10r=vs(g[4]), g10i=vs(g[5]), g11r=vs(g[6]), g11i=vs(g[7]);
#pragma unroll
  for (int p=0;p<8;++p) if (!(p&PM)) {
    const int q = p|PM;
    v2f r0=R[p], i0=I[p], r1=R[q], i1=I[q];
    R[p] = g00r*r0 - g00i*i0 + g01r*r1 - g01i*i1;
    I[p] = g00r*i0 + g00i*r0 + g01r*i1 + g01i*r1;
    R[q] = g10r*r0 - g10i*i0 + g11r*r1 - g11i*i1;
    I[q] = g10r*i0 + g10i*r0 + g11r*i1 + g11i*r1;
  }
}

// wire 9: intra-pair
__device__ __forceinline__ void g_local9(v2f (&R)[8], v2f (&I)[8], const float* g)
{
  const v2f Gr0 = (v2f){g[0], g[4]};
  const v2f Gi0 = (v2f){g[1], g[5]};
  const v2f Gr1 = (v2f){g[2], g[6]};
  const v2f Gi1 = (v2f){g[3], g[7]};
#pragma unroll
  for (int p=0;p<8;++p) {
    v2f Rx = vs(R[p].x), Ix = vs(I[p].x);
    v2f Ry = vs(R[p].y), Iy = vs(I[p].y);
    R[p] = Gr0*Rx - Gi0*Ix + Gr1*Ry - Gi1*Iy;
    I[p] = Gr0*Ix + Gi0*Rx + Gr1*Iy + Gi1*Ry;
  }
}

// ---------------- CNOT ring --------------------------------------------------
__device__ __forceinline__ void cnot_ring(v2f (&R)[8], v2f (&I)[8],
                                          int addrg, int lane, bool c5)
{
#pragma unroll
  for (int p=0;p<8;++p) R[p] = bperm2(addrg, R[p]);
#pragma unroll
  for (int p=0;p<8;++p) I[p] = bperm2(addrg, I[p]);
#pragma unroll
  for (int p=0;p<4;++p) {
    v2f a=R[p], b=R[p|4];
    R[p]   = c5 ? b : a;
    R[p|4] = c5 ? a : b;
    v2f ai=I[p], bi=I[p|4];
    I[p]   = c5 ? bi : ai;
    I[p|4] = c5 ? ai : bi;
  }
#pragma unroll
  for (int p=0;p<8;++p) if ((p&4)&&!(p&2)) {
    const int q=p|2;
    v2f t=R[p]; R[p]=R[q]; R[q]=t;
    t=I[p]; I[p]=I[q]; I[q]=t;
  }
#pragma unroll
  for (int p=0;p<8;++p) if ((p&2)&&!(p&1)) {
    const int q=p|1;
    v2f t=R[p]; R[p]=R[q]; R[q]=t;
    t=I[p]; I[p]=I[q]; I[q]=t;
  }
#pragma unroll
  for (int p=1;p<8;p+=2) {
    R[p] = __builtin_shufflevector(R[p],R[p],1,0);
    I[p] = __builtin_shufflevector(I[p],I[p],1,0);
  }
#pragma unroll
  for (int p=0;p<8;++p) {
    R[p].y = xor32f(R[p].y, lane);
    I[p].y = xor32f(I[p].y, lane);
  }
}

// ---------------- k_pre: BN partial stats (320 blocks, well-spread) ---------
// block b: feature f = b>>3, slice = b&7 (1024 samples). Writes ps[b*2+{0,1}].
__global__ __launch_bounds__(256) void k_pre(const float* __restrict__ x,
    const float* __restrict__ qw, const float* __restrict__ qb,
    float* __restrict__ ps)
{
  const int f = blockIdx.x >> 3, slice = blockIdx.x & 7;
  const int t = threadIdx.x;
  __shared__ float wf[40];
  __shared__ float a1[4], a2[4];
  if (t < 40) wf[t] = qw[f*40 + t];
  __syncthreads();
  const float bf = qb[f];
  float s1 = 0.f, s2 = 0.f;
#pragma unroll
  for (int i = 0; i < 4; ++i) {
    const int s = slice*1024 + t + i*256;
    const float4* xr = (const float4*)(x + s*40);
    float d = bf;
#pragma unroll
    for (int q = 0; q < 10; ++q) {
      float4 v = xr[q];
      d = fmaf(v.x, wf[4*q+0], d);
      d = fmaf(v.y, wf[4*q+1], d);
      d = fmaf(v.z, wf[4*q+2], d);
      d = fmaf(v.w, wf[4*q+3], d);
    }
    s1 += d; s2 = fmaf(d, d, s2);
  }
  s1 = dsum(s1); s2 = dsum(s2);
  const int lane = t & 63, wid = t >> 6;
  if (lane == 63) { a1[wid] = s1; a2[wid] = s2; }
  __syncthreads();
  if (t == 0) {
    ps[blockIdx.x*2+0] = a1[0]+a1[1]+a1[2]+a1[3];
    ps[blockIdx.x*2+1] = a2[0]+a2[1]+a2[2]+a2[3];
  }
}

// ---------------- k_qnn: everything else ------------------------------------

#define GEN10(PTR) \
  g_cross_x32(R,I,lane,h0,(PTR)+0);  g_cross_x16(R,I,lane,h1,(PTR)+8);  \
  g_cross_x8 (R,I,lane,h2,(PTR)+16); g_cross_x4 (R,I,lane,h3,(PTR)+24); \
  g_cross_x2 (R,I,lane,h4,(PTR)+32); g_cross_x1 (R,I,lane,h5,(PTR)+40); \
  g_localp<4>(R,I,(PTR)+48);   g_localp<2>(R,I,(PTR)+56);   \
  g_localp<1>(R,I,(PTR)+64);   g_local9(R,I,(PTR)+72);

// Plain launch bounds — min-waves arg causes spill cascade (see header).
__global__ __launch_bounds__(256) void k_qnn(const float* __restrict__ x,
    const float* __restrict__ qlin_w, const float* __restrict__ qlin_b,
    const float* __restrict__ ps,
    const float* __restrict__ gamma, const float* __restrict__ beta,
    const float* __restrict__ rz1, const float* __restrict__ ry1,
    const float* __restrict__ rz2,
    const float* __restrict__ clin_w, const float* __restrict__ clin_b,
    const float* __restrict__ lin_w, const float* __restrict__ lin_b,
    float* __restrict__ out)
{
  const int tix  = threadIdx.x;
  const int lane = tix & 63;
  const int wv   = tix >> 6;

  __shared__ float Gbuf[40][8];     // fused param gates Rz2*Ry1*Rz1
  __shared__ float bnA[40], bnC[40];
  __shared__ float Ebuf[4][10][8];
  __shared__ float Fbuf[4][3][10][8];
  __shared__ float xs [4][40];      // raw x rows (reused by epilogue)
  __shared__ float xqs[4][40];      // xq = x@qlin^T+b for the 4 samples
  __shared__ float x1s[4][40];      // QNN outputs
  __shared__ float x2s[4][40];      // relu branch

  // ---- stage x rows + gate consts + BN reduce, all in one barrier group
  if (tix < 160) xs[tix/40][tix%40] = x[blockIdx.x*160 + tix];
  if (tix >= 160 && tix < 200) {
    const int gi = tix - 160;
    float g = rz1[gi], ay = ry1[gi], bz = rz2[gi];
    float ca, sa, cp, sp, cm, sm;
    sincosf(0.5f*ay, &sa, &ca);
    sincosf(0.5f*(bz+g), &sp, &cp);
    sincosf(0.5f*(bz-g), &sm, &cm);
    float* G = &Gbuf[gi][0];
    G[0]= ca*cp; G[1]=-ca*sp;
    G[2]=-sa*cm; G[3]= sa*sm;
    G[4]= sa*cm; G[5]= sa*sm;
    G[6]= ca*cp; G[7]= ca*sp;
  }
  if (tix >= 200 && tix < 240) {
    const int f = tix - 200;
    float s1 = 0.f, s2 = 0.f;
#pragma unroll
    for (int k = 0; k < 8; ++k) {
      s1 += ps[(f*8+k)*2+0];
      s2 += ps[(f*8+k)*2+1];
    }
    float mu  = s1 * (1.f/8192.f);
    float var = s2 * (1.f/8192.f) - mu*mu;
    float a = gamma[f] * rsqrtf(var + 1e-5f);
    bnA[f] = a; bnC[f] = beta[f] - mu*a;
  }
  __syncthreads();

  // ---- xq for our 4 samples (weights L2-hot, aligned float4 rows)
  if (tix < 160) {
    const int sl = tix/40, f = tix - sl*40;
    const float4* qw = (const float4*)(qlin_w + f*40);
    float acc = qlin_b[f];
#pragma unroll
    for (int q = 0; q < 10; ++q) {
      float4 v = qw[q];
      acc = fmaf(v.x, xs[sl][4*q+0], acc);
      acc = fmaf(v.y, xs[sl][4*q+1], acc);
      acc = fmaf(v.z, xs[sl][4*q+2], acc);
      acc = fmaf(v.w, xs[sl][4*q+3], acc);
    }
    xqs[sl][f] = acc;
  }
  __syncthreads();

  // ---- per-sample fused encoder matrix per wire: Rx(f3) Rz(f2) Ry(f1) Rx(f0)
  if (lane < 10) {
    const int i = lane;
    const int f = 4*i;
    float h0 = 0.5f * fmaf(xqs[wv][f+0], bnA[f+0], bnC[f+0]);
    float h1 = 0.5f * fmaf(xqs[wv][f+1], bnA[f+1], bnC[f+1]);
    float h2 = 0.5f * fmaf(xqs[wv][f+2], bnA[f+2], bnC[f+2]);
    float h3 = 0.5f * fmaf(xqs[wv][f+3], bnA[f+3], bnC[f+3]);
    float c0,s0,c1,s1,c2,s2,c3,s3;
    sincosf(h0,&s0,&c0); sincosf(h1,&s1,&c1);
    sincosf(h2,&s2,&c2); sincosf(h3,&s3,&c3);
    float A00r=c1*c0, A00i= s1*s0;
    float A01r=-s1*c0, A01i=-c1*s0;
    float A10r= s1*c0, A10i=-c1*s0;
    float A11r= c1*c0, A11i=-s1*s0;
    float B00r = A00r*c2 + A00i*s2, B00i = A00i*c2 - A00r*s2;
    float B01r = A01r*c2 + A01i*s2, B01i = A01i*c2 - A01r*s2;
    float B10r = A10r*c2 - A10i*s2, B10i = A10i*c2 + A10r*s2;
    float B11r = A11r*c2 - A11i*s2, B11i = A11i*c2 + A11r*s2;
    float* e = &Ebuf[wv][i][0];
    e[0] = c3*B00r + s3*B10i;  e[1] = c3*B00i - s3*B10r;
    e[2] = c3*B01r + s3*B11i;  e[3] = c3*B01i - s3*B11r;
    e[4] = c3*B10r + s3*B00i;  e[5] = c3*B10i - s3*B00r;
    e[6] = c3*B11r + s3*B01i;  e[7] = c3*B11i - s3*B01r;
  }

  // ---- fused F_k = U_{k+1} * E (same wave reads its own Ebuf rows)
  if (lane < 30) {
    const int k = lane/10, i = lane - k*10;
    const float* U = &Gbuf[(k+1)*10 + i][0];
    const float* E = &Ebuf[wv][i][0];
    float u00r=U[0],u00i=U[1],u01r=U[2],u01i=U[3],u10r=U[4],u10i=U[5],u11r=U[6],u11i=U[7];
    float e00r=E[0],e00i=E[1],e01r=E[2],e01i=E[3],e10r=E[4],e10i=E[5],e11r=E[6],e11i=E[7];
    float* F = &Fbuf[wv][k][i][0];
    F[0] = u00r*e00r - u00i*e00i + u01r*e10r - u01i*e10i;
    F[1] = u00r*e00i + u00i*e00r + u01r*e10i + u01i*e10r;
    F[2] = u00r*e01r - u00i*e01i + u01r*e11r - u01i*e11i;
    F[3] = u00r*e01i + u00i*e01r + u01r*e11i + u01i*e11r;
    F[4] = u10r*e00r - u10i*e00i + u11r*e10r - u11i*e10i;
    F[5] = u10r*e00i + u10i*e00r + u11r*e10i + u11i*e10r;
    F[6] = u10r*e01r - u10i*e01i + u11r*e11r - u11i*e11i;
    F[7] = u10r*e01i + u10i*e01r + u11r*e11i + u11i*e11r;
  }

  const bool h0 = (lane & 32) != 0;
  const bool h1 = (lane & 16) != 0;
  const bool h2 = (lane &  8) != 0;
  const bool h3 = (lane &  4) != 0;
  const bool h4 = (lane &  2) != 0;
  const bool h5 = (lane &  1) != 0;
  const int addrg = (lane ^ (lane >> 1)) << 2;

  // ---- init: state = U0 |0..0>  (product state, column 0 per wire)
  v2f R[8], I[8];
  {
    float cr = 1.f, ci = 0.f;
#pragma unroll
    for (int w=0; w<6; ++w) {
      const float g0r = Gbuf[w][0], g0i = Gbuf[w][1];
      const float g1r = Gbuf[w][4], g1i = Gbuf[w][5];
      const bool bset = (lane >> (5-w)) & 1;
      const float ar = bset ? g1r : g0r, ai = bset ? g1i : g0i;
      const float tr = cr*ar - ci*ai, ti = cr*ai + ci*ar;
      cr = tr; ci = ti;
    }
    float p67r[4], p67i[4], p89r[4], p89i[4];
#pragma unroll
    for (int b6=0;b6<2;++b6)
#pragma unroll
      for (int b7=0;b7<2;++b7) {
        const float x6r = Gbuf[6][4*b6], x6i = Gbuf[6][4*b6+1];
        const float x7r = Gbuf[7][4*b7], x7i = Gbuf[7][4*b7+1];
        p67r[b6*2+b7] = x6r*x7r - x6i*x7i;
        p67i[b6*2+b7] = x6r*x7i + x6i*x7r;
      }
#pragma unroll
    for (int b8=0;b8<2;++b8)
#pragma unroll
      for (int b9=0;b9<2;++b9) {
        const float x8r = Gbuf[8][4*b8], x8i = Gbuf[8][4*b8+1];
        const float x9r = Gbuf[9][4*b9], x9i = Gbuf[9][4*b9+1];
        p89r[b8*2+b9] = x8r*x9r - x8i*x9i;
        p89i[b8*2+b9] = x8r*x9i + x8i*x9r;
      }
#pragma unroll
    for (int m=0;m<4;++m) {
      const float tr = p67r[m]*cr - p67i[m]*ci;
      const float ti = p67r[m]*ci + p67i[m]*cr;
      p67r[m]=tr; p67i[m]=ti;
    }
#pragma unroll
    for (int p=0;p<8;++p) {
      const int hi = p>>1, b8 = p&1;
      const v2f Pr = (v2f){p89r[2*b8], p89r[2*b8+1]};
      const v2f Pi = (v2f){p89i[2*b8], p89i[2*b8+1]};
      R[p] = vs(p67r[hi])*Pr - vs(p67i[hi])*Pi;
      I[p] = vs(p67r[hi])*Pi + vs(p67i[hi])*Pr;
    }
  }

  // ---- main circuit: 4 rings interleaved with 3 fused layers
  cnot_ring(R,I,addrg,lane,h5);
  { const float* F = &Fbuf[wv][0][0][0]; GEN10(F) }
  cnot_ring(R,I,addrg,lane,h5);
  { const float* F = &Fbuf[wv][1][0][0]; GEN10(F) }
  cnot_ring(R,I,addrg,lane,h5);
  { const float* F = &Fbuf[wv][2][0][0]; GEN10(F) }
  cnot_ring(R,I,addrg,lane,h5);

  float* dst = &x1s[wv][0];

  // ---- outs[0]: <Z_w> from probabilities
  {
    v2f pv[8];
#pragma unroll
    for (int p=0;p<8;++p) pv[p] = R[p]*R[p] + I[p]*I[p];
    v2f T8 = (pv[0]-pv[1]) + (pv[2]-pv[3]) + (pv[4]-pv[5]) + (pv[6]-pv[7]);
    v2f aa[4];
#pragma unroll
    for (int m=0;m<4;++m) aa[m] = pv[2*m] + pv[2*m+1];
    v2f T7 = (aa[0]-aa[1]) + (aa[2]-aa[3]);
    v2f T6 = (aa[0]+aa[1]) - (aa[2]+aa[3]);
    v2f S  = (aa[0]+aa[1]) + (aa[2]+aa[3]);
    float q8 = T8.x + T8.y;
    float q7 = T7.x + T7.y;
    float q6 = T6.x + T6.y;
    float q9 = S.x - S.y;
    float P  = S.x + S.y;

    float v = P;
    { float pt = xor1f (v,lane); v = h5 ? (pt - v) : (pt + v); }
    { float pt = xor2f (v,lane); v = h4 ? (pt - v) : (pt + v); }
    { float pt = xor4f (v,lane); v = h3 ? (pt - v) : (pt + v); }
    { float pt = xor8f (v,lane); v = h2 ? (pt - v) : (pt + v); }
    { float pt = xor16f(v,lane); v = h1 ? (pt - v) : (pt + v); }
    { float pt = xor32f(v,lane); v = h0 ? (pt - v) : (pt + v); }

    q6 = dsum(q6); q7 = dsum(q7); q8 = dsum(q8); q9 = dsum(q9);

    if (lane==32) dst[0]=v;
    if (lane==16) dst[1]=v;
    if (lane== 8) dst[2]=v;
    if (lane== 4) dst[3]=v;
    if (lane== 2) dst[4]=v;
    if (lane== 1) dst[5]=v;
    if (lane==63){ dst[6]=q6; dst[7]=q7; dst[8]=q8; dst[9]=q9; }
  }

  // ---- outs[1]=<X>, outs[2]=outs[3]=-<Y>, direct from psi0
#define XYC(PFN,HW,W) { \
    v2f U=vs(0.f), V=vs(0.f); \
    _Pragma("unroll") \
    for (int p=0;p<8;++p) { \
      v2f PR = PFN(R[p],lane); \
      v2f PI = PFN(I[p],lane); \
      U += R[p]*PR + I[p]*PI; \
      V += I[p]*PR - R[p]*PI; \
    } \
    float u = U.x + U.y; \
    float vv = V.x + V.y; \
    vv = (HW) ? vv : -vv; \
    u = dsum(u); vv = dsum(vv); \
    if (lane==63){ dst[10+(W)]=u; dst[20+(W)]=vv; dst[30+(W)]=vv; } \
  }
  XYC(xor32v,h0,0) XYC(xor16v,h1,1) XYC(xor8v,h2,2)
  XYC(xor4v ,h3,3) XYC(xor2v ,h4,4) XYC(xor1v,h5,5)
#undef XYC

#define XYL(PM,W) { \
    v2f U=vs(0.f), V=vs(0.f); \
    _Pragma("unroll") \
    for (int p=0;p<8;++p) if (!(p&(PM))) { \
      const int q=p|(PM); \
      U += R[p]*R[q] + I[p]*I[q]; \
      V += I[p]*R[q] - R[p]*I[q]; \
    } \
    float u = U.x + U.y; \
    float vv = V.x + V.y; \
    u = dsum(u); vv = dsum(vv); \
    if (lane==63){ dst[10+(W)]=2.f*u; float y=-2.f*vv; dst[20+(W)]=y; dst[30+(W)]=y; } \
  }
  XYL(4,6) XYL(2,7) XYL(1,8)
#undef XYL

  {
    float u=0.f, vv=0.f;
#pragma unroll
    for (int p=0;p<8;++p) {
      u  = fmaf(R[p].x, R[p].y, u);  u  = fmaf(I[p].x, I[p].y, u);
      vv = fmaf(I[p].x, R[p].y, vv); vv = fmaf(-R[p].x, I[p].y, vv);
    }
    u = dsum(u); vv = dsum(vv);
    if (lane==63){ dst[19]=2.f*u; float y=-2.f*vv; dst[29]=y; dst[39]=y; }
  }

  // ---- fused epilogue: x2 = relu(x@clin^T+b); out = [x1,x2]@lin^T + b
  __syncthreads();
  if (tix < 160) {
    const int sl = tix/40, f = tix - sl*40;
    const float4* cw = (const float4*)(clin_w + f*40);
    float acc = clin_b[f];
#pragma unroll
    for (int q = 0; q < 10; ++q) {
      float4 v = cw[q];
      acc = fmaf(v.x, xs[sl][4*q+0], acc);
      acc = fmaf(v.y, xs[sl][4*q+1], acc);
      acc = fmaf(v.z, xs[sl][4*q+2], acc);
      acc = fmaf(v.w, xs[sl][4*q+3], acc);
    }
    x2s[sl][f] = fmaxf(acc, 0.f);
  }
  __syncthreads();
  if (tix < 160) {
    const int sl = tix/40, f = tix - sl*40;
    const float4* lw = (const float4*)(lin_w + f*80);
    float o = lin_b[f];
#pragma unroll
    for (int q = 0; q < 10; ++q) {
      float4 v = lw[q];
      o = fmaf(v.x, x1s[sl][4*q+0], o);
      o = fmaf(v.y, x1s[sl][4*q+1], o);
      o = fmaf(v.z, x1s[sl][4*q+2], o);
      o = fmaf(v.w, x1s[sl][4*q+3], o);
    }
#pragma unroll
    for (int q = 10; q < 20; ++q) {
      float4 v = lw[q];
      o = fmaf(v.x, x2s[sl][4*(q-10)+0], o);
      o = fmaf(v.y, x2s[sl][4*(q-10)+1], o);
      o = fmaf(v.z, x2s[sl][4*(q-10)+2], o);
      o = fmaf(v.w, x2s[sl][4*(q-10)+3], o);
    }
    out[blockIdx.x*160 + tix] = o;
  }
}

// ---------------- launch ---------------------------------------------------
extern "C" void kernel_launch(void* const* d_in, const int* in_sizes, int n_in,
                              void* d_out, int out_size, void* d_ws, size_t ws_size,
                              hipStream_t stream)
{
  const float* x      = (const float*)d_in[0];
  const float* qlin_w = (const float*)d_in[1];
  const float* qlin_b = (const float*)d_in[2];
  const float* bn_g   = (const float*)d_in[3];
  const float* bn_b   = (const float*)d_in[4];
  const float* clin_w = (const float*)d_in[5];
  const float* clin_b = (const float*)d_in[6];
  const float* lin_w  = (const float*)d_in[7];
  const float* lin_b  = (const float*)d_in[8];
  const float* rz1    = (const float*)d_in[9];
  const float* ry1    = (const float*)d_in[10];
  const float* rz2    = (const float*)d_in[11];

  float* ps  = (float*)d_ws;     // 640 floats of partials
  float* out = (float*)d_out;

  hipLaunchKernelGGL(k_pre, dim3(320),  dim3(256), 0, stream, x, qlin_w, qlin_b, ps);
  hipLaunchKernelGGL(k_qnn, dim3(2048), dim3(256), 0, stream,
                     x, qlin_w, qlin_b, ps, bn_g, bn_b, rz1, ry1, rz2,
                     clin_w, clin_b, lin_w, lin_b, out);
}

// Round 12
// 166.346 us; speedup vs baseline: 1.1874x; 1.0639x over previous
//
#include <hip/hip_runtime.h>
#include <math.h>

// ---------------------------------------------------------------------------
// QINRLayer: Linear+BN -> 10-qubit QNN (statevector sim) -> classical branch
// TWO launches:
//   k_pre : BN partial stats, 320 blocks (40 features x 8 sample-slices)
//   k_qnn : partial-reduce + xq recompute (4 samples/block) + gates + QNN
//           + fused epilogue
//
// One wave per sample; 1024 complex amps in registers, PACKED as float2:
//   pair p holds j=2p (.x) and j=2p+1 (.y);  k = lane*16 + j.
//   wire w (0=MSB) <-> lane bit (5-w) for w<6; wires 6,7,8 <-> pair bits 2,1,0;
//   wire 9 <-> intra-pair half.
// Pipe balance (R7: all-DS bound; R9: all-VALU 80% bound; optimum between):
//   xor1/2 quad_perm DPP (1 VALU); xor4/8 ds_swizzle (1 DS, was 3 VALU);
//   xor16/32 permlane*_swap (2 VALU). Ring gray-perm on ds_bpermute.
//
// Circuit algebra (all exact):
//   U0|0..0> product state; ring #1 is a GF(2)-linear basis permutation of a
//   product state -> FUSED into init: amp(L,j) = c(gray(L)^48*(j&1)) *
//   phi67[gray4(j)^8*(L&1) bits] * phi89[...]   (derivation matches R6's
//   verified single-permutation gather; parity(gray(L)) == L&1).
//   F_k = U_{k+1} * E fused layers; 3 rings remain.
//   outs[1]=<X>, outs[2]=outs[3]=-<Y> direct from psi0 (H*H=I, rz3 diagonal).
//
// HARD-WON: do NOT set min-waves-per-EU in __launch_bounds__ (R2/R3 spill
// cascade). R8: no same-address atomics across 1024 blocks. R10: no grid-40
// kernels (216 CUs idle). ~73us of total is fixed harness/graph overhead.
// ---------------------------------------------------------------------------

typedef float v2f __attribute__((ext_vector_type(2)));
typedef unsigned uiv2 __attribute__((ext_vector_type(2)));

__device__ __forceinline__ float bperm1(int addr, float v){
  return __int_as_float(__builtin_amdgcn_ds_bpermute(addr, __float_as_int(v)));
}
__device__ __forceinline__ v2f bperm2(int addr, v2f v){
  v2f r; r.x = bperm1(addr, v.x); r.y = bperm1(addr, v.y); return r;
}
__device__ __forceinline__ v2f vs(float x){ return (v2f){x,x}; }

// ---- cross-lane helpers -----------------------------------------------------
template<int C>
__device__ __forceinline__ float dppf(float x){
  return __int_as_float(__builtin_amdgcn_update_dpp(0, __float_as_int(x),
                                                    C, 0xf, 0xf, true));
}
#define QP_X1 0xB1   // quad_perm [1,0,3,2]  == xor 1
#define QP_X2 0x4E   // quad_perm [2,3,0,1]  == xor 2

__device__ __forceinline__ float xor1f(float x, int /*lane*/){ return dppf<QP_X1>(x); }
__device__ __forceinline__ float xor2f(float x, int /*lane*/){ return dppf<QP_X2>(x); }

// xor4/xor8 on the DS pipe: ds_swizzle BitMode (xor<<10)|0x1F, within 32-lane
// groups (masks 4,8 never cross the group boundary).
__device__ __forceinline__ float xor4f(float x, int /*lane*/){
  return __int_as_float(__builtin_amdgcn_ds_swizzle(__float_as_int(x), 0x101F));
}
__device__ __forceinline__ float xor8f(float x, int /*lane*/){
  return __int_as_float(__builtin_amdgcn_ds_swizzle(__float_as_int(x), 0x201F));
}

#if __has_builtin(__builtin_amdgcn_permlane16_swap) && __has_builtin(__builtin_amdgcn_permlane32_swap)
__device__ __forceinline__ float xor16f(float x, int lane){
  uiv2 r = __builtin_amdgcn_permlane16_swap(__float_as_uint(x), __float_as_uint(x),
                                            false, false);
  return __uint_as_float((lane & 16) ? r.x : r.y);
}
__device__ __forceinline__ float xor32f(float x, int lane){
  uiv2 r = __builtin_amdgcn_permlane32_swap(__float_as_uint(x), __float_as_uint(x),
                                            false, false);
  return __uint_as_float((lane & 32) ? r.x : r.y);
}
#else
__device__ __forceinline__ float xor16f(float x, int lane){ return bperm1((lane^16)<<2, x); }
__device__ __forceinline__ float xor32f(float x, int lane){ return bperm1((lane^32)<<2, x); }
#endif

#define DEF_XORV(NAME, F1) \
__device__ __forceinline__ v2f NAME(v2f v, int lane){ \
  v2f r; r.x = F1(v.x,lane); r.y = F1(v.y,lane); return r; }
DEF_XORV(xor1v,  xor1f)
DEF_XORV(xor2v,  xor2f)
DEF_XORV(xor4v,  xor4f)
DEF_XORV(xor8v,  xor8f)
DEF_XORV(xor16v, xor16f)
DEF_XORV(xor32v, xor32f)

// full wave64 sum; valid in lane 63 only
__device__ __forceinline__ float dsum(float x){
  x += dppf<0x111>(x);   // row_shr:1
  x += dppf<0x112>(x);   // row_shr:2
  x += dppf<0x114>(x);   // row_shr:4
  x += dppf<0x118>(x);   // row_shr:8
  x += dppf<0x142>(x);   // row_bcast:15
  x += dppf<0x143>(x);   // row_bcast:31
  return x;
}

// ---------------- gate primitives (packed state) ----------------------------

#define DEF_GCROSS(NAME, PFN) \
__device__ __forceinline__ void NAME(v2f (&R)[8], v2f (&I)[8], int lane, bool hi, \
                                     const float* g){ \
  const float gar = hi ? g[6] : g[0], gai = hi ? g[7] : g[1]; \
  const float gbr = hi ? g[4] : g[2], gbi = hi ? g[5] : g[3]; \
  const v2f A=vs(gar), B=vs(gai), C=vs(gbr), D=vs(gbi); \
  _Pragma("unroll") \
  for (int p=0;p<8;++p){ \
    v2f PR = PFN(R[p],lane); \
    v2f PI = PFN(I[p],lane); \
    v2f nr = A*R[p] - B*I[p] + C*PR - D*PI; \
    v2f ni = A*I[p] + B*R[p] + C*PI + D*PR; \
    R[p]=nr; I[p]=ni; } \
}
DEF_GCROSS(g_cross_x32, xor32v)
DEF_GCROSS(g_cross_x16, xor16v)
DEF_GCROSS(g_cross_x8,  xor8v)
DEF_GCROSS(g_cross_x4,  xor4v)
DEF_GCROSS(g_cross_x2,  xor2v)
DEF_GCROSS(g_cross_x1,  xor1v)

// local wires 6,7,8 -> pair masks 4,2,1
template<int PM>
__device__ __forceinline__ void g_localp(v2f (&R)[8], v2f (&I)[8], const float* g)
{
  const v2f g00r=vs(g[0]), g00i=vs(g[1]), g01r=vs(g[2]), g01i=vs(g[3]);
  const v2f g10r=vs(g[4]), g10i=vs(g[5]), g11r=vs(g[6]), g11i=vs(g[7]);
#pragma unroll
  for (int p=0;p<8;++p) if (!(p&PM)) {
    const int q = p|PM;
    v2f r0=R[p], i0=I[p], r1=R[q], i1=I[q];
    R[p] = g00r*r0 - g00i*i0 + g01r*r1 - g01i*i1;
    I[p] = g00r*i0 + g00i*r0 + g01r*i1 + g01i*r1;
    R[q] = g10r*r0 - g10i*i0 + g11r*r1 - g11i*i1;
    I[q] = g10r*i0 + g10i*r0 + g11r*i1 + g11i*r1;
  }
}

// wire 9: intra-pair
__device__ __forceinline__ void g_local9(v2f (&R)[8], v2f (&I)[8], const float* g)
{
  const v2f Gr0 = (v2f){g[0], g[4]};
  const v2f Gi0 = (v2f){g[1], g[5]};
  const v2f Gr1 = (v2f){g[2], g[6]};
  const v2f Gi1 = (v2f){g[3], g[7]};
#pragma unroll
  for (int p=0;p<8;++p) {
    v2f Rx = vs(R[p].x), Ix = vs(I[p].x);
    v2f Ry = vs(R[p].y), Iy = vs(I[p].y);
    R[p] = Gr0*Rx - Gi0*Ix + Gr1*Ry - Gi1*Iy;
    I[p] = Gr0*Ix + Gi0*Rx + Gr1*Iy + Gi1*Ry;
  }
}

// ---------------- CNOT ring --------------------------------------------------
__device__ __forceinline__ void cnot_ring(v2f (&R)[8], v2f (&I)[8],
                                          int addrg, int lane, bool c5)
{
#pragma unroll
  for (int p=0;p<8;++p) R[p] = bperm2(addrg, R[p]);
#pragma unroll
  for (int p=0;p<8;++p) I[p] = bperm2(addrg, I[p]);
#pragma unroll
  for (int p=0;p<4;++p) {
    v2f a=R[p], b=R[p|4];
    R[p]   = c5 ? b : a;
    R[p|4] = c5 ? a : b;
    v2f ai=I[p], bi=I[p|4];
    I[p]   = c5 ? bi : ai;
    I[p|4] = c5 ? ai : bi;
  }
#pragma unroll
  for (int p=0;p<8;++p) if ((p&4)&&!(p&2)) {
    const int q=p|2;
    v2f t=R[p]; R[p]=R[q]; R[q]=t;
    t=I[p]; I[p]=I[q]; I[q]=t;
  }
#pragma unroll
  for (int p=0;p<8;++p) if ((p&2)&&!(p&1)) {
    const int q=p|1;
    v2f t=R[p]; R[p]=R[q]; R[q]=t;
    t=I[p]; I[p]=I[q]; I[q]=t;
  }
#pragma unroll
  for (int p=1;p<8;p+=2) {
    R[p] = __builtin_shufflevector(R[p],R[p],1,0);
    I[p] = __builtin_shufflevector(I[p],I[p],1,0);
  }
#pragma unroll
  for (int p=0;p<8;++p) {
    R[p].y = xor32f(R[p].y, lane);
    I[p].y = xor32f(I[p].y, lane);
  }
}

// ---------------- k_pre: BN partial stats (320 blocks) ----------------------
__global__ __launch_bounds__(256) void k_pre(const float* __restrict__ x,
    const float* __restrict__ qw, const float* __restrict__ qb,
    float* __restrict__ ps)
{
  const int f = blockIdx.x >> 3, slice = blockIdx.x & 7;
  const int t = threadIdx.x;
  __shared__ float wf[40];
  __shared__ float a1[4], a2[4];
  if (t < 40) wf[t] = qw[f*40 + t];
  __syncthreads();
  const float bf = qb[f];
  float s1 = 0.f, s2 = 0.f;
#pragma unroll
  for (int i = 0; i < 4; ++i) {
    const int s = slice*1024 + t + i*256;
    const float4* xr = (const float4*)(x + s*40);
    float d = bf;
#pragma unroll
    for (int q = 0; q < 10; ++q) {
      float4 v = xr[q];
      d = fmaf(v.x, wf[4*q+0], d);
      d = fmaf(v.y, wf[4*q+1], d);
      d = fmaf(v.z, wf[4*q+2], d);
      d = fmaf(v.w, wf[4*q+3], d);
    }
    s1 += d; s2 = fmaf(d, d, s2);
  }
  s1 = dsum(s1); s2 = dsum(s2);
  const int lane = t & 63, wid = t >> 6;
  if (lane == 63) { a1[wid] = s1; a2[wid] = s2; }
  __syncthreads();
  if (t == 0) {
    ps[blockIdx.x*2+0] = a1[0]+a1[1]+a1[2]+a1[3];
    ps[blockIdx.x*2+1] = a2[0]+a2[1]+a2[2]+a2[3];
  }
}

// ---------------- k_qnn: everything else ------------------------------------

#define GEN10(PTR) \
  g_cross_x32(R,I,lane,h0,(PTR)+0);  g_cross_x16(R,I,lane,h1,(PTR)+8);  \
  g_cross_x8 (R,I,lane,h2,(PTR)+16); g_cross_x4 (R,I,lane,h3,(PTR)+24); \
  g_cross_x2 (R,I,lane,h4,(PTR)+32); g_cross_x1 (R,I,lane,h5,(PTR)+40); \
  g_localp<4>(R,I,(PTR)+48);   g_localp<2>(R,I,(PTR)+56);   \
  g_localp<1>(R,I,(PTR)+64);   g_local9(R,I,(PTR)+72);

// Plain launch bounds — min-waves arg causes spill cascade (see header).
__global__ __launch_bounds__(256) void k_qnn(const float* __restrict__ x,
    const float* __restrict__ qlin_w, const float* __restrict__ qlin_b,
    const float* __restrict__ ps,
    const float* __restrict__ gamma, const float* __restrict__ beta,
    const float* __restrict__ rz1, const float* __restrict__ ry1,
    const float* __restrict__ rz2,
    const float* __restrict__ clin_w, const float* __restrict__ clin_b,
    const float* __restrict__ lin_w, const float* __restrict__ lin_b,
    float* __restrict__ out)
{
  const int tix  = threadIdx.x;
  const int lane = tix & 63;
  const int wv   = tix >> 6;

  __shared__ float Gbuf[40][8];     // fused param gates Rz2*Ry1*Rz1
  __shared__ float bnA[40], bnC[40];
  __shared__ float Ebuf[4][10][8];
  __shared__ float Fbuf[4][3][10][8];
  __shared__ float xs [4][40];
  __shared__ float xqs[4][40];
  __shared__ float x1s[4][40];
  __shared__ float x2s[4][40];

  // ---- stage x rows + gate consts + BN reduce, one barrier group
  if (tix < 160) xs[tix/40][tix%40] = x[blockIdx.x*160 + tix];
  if (tix >= 160 && tix < 200) {
    const int gi = tix - 160;
    float g = rz1[gi], ay = ry1[gi], bz = rz2[gi];
    float ca, sa, cp, sp, cm, sm;
    sincosf(0.5f*ay, &sa, &ca);
    sincosf(0.5f*(bz+g), &sp, &cp);
    sincosf(0.5f*(bz-g), &sm, &cm);
    float* G = &Gbuf[gi][0];
    G[0]= ca*cp; G[1]=-ca*sp;
    G[2]=-sa*cm; G[3]= sa*sm;
    G[4]= sa*cm; G[5]= sa*sm;
    G[6]= ca*cp; G[7]= ca*sp;
  }
  if (tix >= 200 && tix < 240) {
    const int f = tix - 200;
    float s1 = 0.f, s2 = 0.f;
#pragma unroll
    for (int k = 0; k < 8; ++k) {
      s1 += ps[(f*8+k)*2+0];
      s2 += ps[(f*8+k)*2+1];
    }
    float mu  = s1 * (1.f/8192.f);
    float var = s2 * (1.f/8192.f) - mu*mu;
    float a = gamma[f] * rsqrtf(var + 1e-5f);
    bnA[f] = a; bnC[f] = beta[f] - mu*a;
  }
  __syncthreads();

  // ---- xq for our 4 samples (weights L2-hot, aligned float4 rows)
  if (tix < 160) {
    const int sl = tix/40, f = tix - sl*40;
    const float4* qw = (const float4*)(qlin_w + f*40);
    float acc = qlin_b[f];
#pragma unroll
    for (int q = 0; q < 10; ++q) {
      float4 v = qw[q];
      acc = fmaf(v.x, xs[sl][4*q+0], acc);
      acc = fmaf(v.y, xs[sl][4*q+1], acc);
      acc = fmaf(v.z, xs[sl][4*q+2], acc);
      acc = fmaf(v.w, xs[sl][4*q+3], acc);
    }
    xqs[sl][f] = acc;
  }
  __syncthreads();

  // ---- per-sample fused encoder matrix per wire: Rx(f3) Rz(f2) Ry(f1) Rx(f0)
  if (lane < 10) {
    const int i = lane;
    const int f = 4*i;
    float h0 = 0.5f * fmaf(xqs[wv][f+0], bnA[f+0], bnC[f+0]);
    float h1 = 0.5f * fmaf(xqs[wv][f+1], bnA[f+1], bnC[f+1]);
    float h2 = 0.5f * fmaf(xqs[wv][f+2], bnA[f+2], bnC[f+2]);
    float h3 = 0.5f * fmaf(xqs[wv][f+3], bnA[f+3], bnC[f+3]);
    float c0,s0,c1,s1,c2,s2,c3,s3;
    sincosf(h0,&s0,&c0); sincosf(h1,&s1,&c1);
    sincosf(h2,&s2,&c2); sincosf(h3,&s3,&c3);
    float A00r=c1*c0, A00i= s1*s0;
    float A01r=-s1*c0, A01i=-c1*s0;
    float A10r= s1*c0, A10i=-c1*s0;
    float A11r= c1*c0, A11i=-s1*s0;
    float B00r = A00r*c2 + A00i*s2, B00i = A00i*c2 - A00r*s2;
    float B01r = A01r*c2 + A01i*s2, B01i = A01i*c2 - A01r*s2;
    float B10r = A10r*c2 - A10i*s2, B10i = A10i*c2 + A10r*s2;
    float B11r = A11r*c2 - A11i*s2, B11i = A11i*c2 + A11r*s2;
    float* e = &Ebuf[wv][i][0];
    e[0] = c3*B00r + s3*B10i;  e[1] = c3*B00i - s3*B10r;
    e[2] = c3*B01r + s3*B11i;  e[3] = c3*B01i - s3*B11r;
    e[4] = c3*B10r + s3*B00i;  e[5] = c3*B10i - s3*B00r;
    e[6] = c3*B11r + s3*B01i;  e[7] = c3*B11i - s3*B01r;
  }

  // ---- fused F_k = U_{k+1} * E (same wave reads its own Ebuf rows)
  if (lane < 30) {
    const int k = lane/10, i = lane - k*10;
    const float* U = &Gbuf[(k+1)*10 + i][0];
    const float* E = &Ebuf[wv][i][0];
    float u00r=U[0],u00i=U[1],u01r=U[2],u01i=U[3],u10r=U[4],u10i=U[5],u11r=U[6],u11i=U[7];
    float e00r=E[0],e00i=E[1],e01r=E[2],e01i=E[3],e10r=E[4],e10i=E[5],e11r=E[6],e11i=E[7];
    float* F = &Fbuf[wv][k][i][0];
    F[0] = u00r*e00r - u00i*e00i + u01r*e10r - u01i*e10i;
    F[1] = u00r*e00i + u00i*e00r + u01r*e10i + u01i*e10r;
    F[2] = u00r*e01r - u00i*e01i + u01r*e11r - u01i*e11i;
    F[3] = u00r*e01i + u00i*e01r + u01r*e11i + u01i*e11r;
    F[4] = u10r*e00r - u10i*e00i + u11r*e10r - u11i*e10i;
    F[5] = u10r*e00i + u10i*e00r + u11r*e10i + u11i*e10r;
    F[6] = u10r*e01r - u10i*e01i + u11r*e11r - u11i*e11i;
    F[7] = u10r*e01i + u10i*e01r + u11r*e11i + u11i*e11r;
  }

  const bool h0 = (lane & 32) != 0;
  const bool h1 = (lane & 16) != 0;
  const bool h2 = (lane &  8) != 0;
  const bool h3 = (lane &  4) != 0;
  const bool h4 = (lane &  2) != 0;
  const bool h5 = (lane &  1) != 0;
  const int addrg = (lane ^ (lane >> 1)) << 2;

  // ---- init: state = ring( U0 |0..0> ) — ring #1 fused analytically.
  //  amp(L,j) = c(L0) * phi6[b3']phi7[b2'] * phi8[b1']phi9[b0'], where
  //  L0 = gray(L) ^ 48*(j&1);  j' bits: b3'=b3^(L&1), b2'=b2^b3, b1'=b1^b2,
  //  b0'=b0^b1.  (verified vs sequential-CNOT gather; see header)
  v2f R[8], I[8];
  {
    const int l0=lane&1, l1=(lane>>1)&1, l2=(lane>>2)&1,
              l3=(lane>>3)&1, l4=(lane>>4)&1, l5=(lane>>5)&1;
    // cs = phi2[l3^l4] phi3[l2^l3] phi4[l1^l2] phi5[l0^l1]
    float csr, csi;
    {
      int b = l3^l4; csr = Gbuf[2][4*b]; csi = Gbuf[2][4*b+1];
      b = l2^l3; float gr=Gbuf[3][4*b], gi=Gbuf[3][4*b+1];
      float tr = csr*gr - csi*gi, ti = csr*gi + csi*gr; csr=tr; csi=ti;
      b = l1^l2; gr=Gbuf[4][4*b]; gi=Gbuf[4][4*b+1];
      tr = csr*gr - csi*gi; ti = csr*gi + csi*gr; csr=tr; csi=ti;
      b = l0^l1; gr=Gbuf[5][4*b]; gi=Gbuf[5][4*b+1];
      tr = csr*gr - csi*gi; ti = csr*gi + csi*gr; csr=tr; csi=ti;
    }
    // ce = phi0[l5] phi1[l4^l5] cs ; co = phi0[1^l5] phi1[1^(l4^l5)] cs
    float cer,cei,cor_,coi;
    {
      const int b5 = l5, b4 = l4^l5;
      float ar = Gbuf[0][4*b5],     ai = Gbuf[0][4*b5+1];
      float br = Gbuf[1][4*b4],     bi = Gbuf[1][4*b4+1];
      float tr = ar*br - ai*bi,     ti = ar*bi + ai*br;
      cer = tr*csr - ti*csi;  cei = tr*csi + ti*csr;
      ar = Gbuf[0][4*(1^b5)]; ai = Gbuf[0][4*(1^b5)+1];
      br = Gbuf[1][4*(1^b4)]; bi = Gbuf[1][4*(1^b4)+1];
      tr = ar*br - ai*bi;     ti = ar*bi + ai*br;
      cor_ = tr*csr - ti*csi; coi = tr*csi + ti*csr;
    }
    // local pair products
    float p67r[4], p67i[4], p89r[4], p89i[4];
#pragma unroll
    for (int b6=0;b6<2;++b6)
#pragma unroll
      for (int b7=0;b7<2;++b7) {
        const float x6r = Gbuf[6][4*b6], x6i = Gbuf[6][4*b6+1];
        const float x7r = Gbuf[7][4*b7], x7i = Gbuf[7][4*b7+1];
        p67r[b6*2+b7] = x6r*x7r - x6i*x7i;
        p67i[b6*2+b7] = x6r*x7i + x6i*x7r;
      }
#pragma unroll
    for (int b8=0;b8<2;++b8)
#pragma unroll
      for (int b9=0;b9<2;++b9) {
        const float x8r = Gbuf[8][4*b8], x8i = Gbuf[8][4*b8+1];
        const float x9r = Gbuf[9][4*b9], x9i = Gbuf[9][4*b9+1];
        p89r[b8*2+b9] = x8r*x9r - x8i*x9i;
        p89i[b8*2+b9] = x8r*x9i + x8i*x9r;
      }
    // t67e = ce*p67, t67o = co*p67
    float ter[4], tei[4], tor_[4], toi[4];
#pragma unroll
    for (int m=0;m<4;++m) {
      ter[m]  = cer*p67r[m] - cei*p67i[m];
      tei[m]  = cer*p67i[m] + cei*p67r[m];
      tor_[m] = cor_*p67r[m] - coi*p67i[m];
      toi[m]  = cor_*p67i[m] + coi*p67r[m];
    }
#pragma unroll
    for (int p=0;p<8;++p) {
      const int b3 = (p>>2)&1, b2 = (p>>1)&1, b1 = p&1;
      const int i67 = ((b3 ^ l0) << 1) | (b2 ^ b3);
      const int b1p = b1 ^ b2;
      const int ix  = (b1p<<1) | b1;
      const int iy  = (b1p<<1) | (1^b1);
      R[p].x = ter[i67]*p89r[ix] - tei[i67]*p89i[ix];
      I[p].x = ter[i67]*p89i[ix] + tei[i67]*p89r[ix];
      R[p].y = tor_[i67]*p89r[iy] - toi[i67]*p89i[iy];
      I[p].y = tor_[i67]*p89i[iy] + toi[i67]*p89r[iy];
    }
  }

  // ---- main circuit: 3 fused layers with 3 remaining rings
  { const float* F = &Fbuf[wv][0][0][0]; GEN10(F) }
  cnot_ring(R,I,addrg,lane,h5);
  { const float* F = &Fbuf[wv][1][0][0]; GEN10(F) }
  cnot_ring(R,I,addrg,lane,h5);
  { const float* F = &Fbuf[wv][2][0][0]; GEN10(F) }
  cnot_ring(R,I,addrg,lane,h5);

  float* dst = &x1s[wv][0];

  // ---- outs[0]: <Z_w> from probabilities
  {
    v2f pv[8];
#pragma unroll
    for (int p=0;p<8;++p) pv[p] = R[p]*R[p] + I[p]*I[p];
    v2f T8 = (pv[0]-pv[1]) + (pv[2]-pv[3]) + (pv[4]-pv[5]) + (pv[6]-pv[7]);
    v2f aa[4];
#pragma unroll
    for (int m=0;m<4;++m) aa[m] = pv[2*m] + pv[2*m+1];
    v2f T7 = (aa[0]-aa[1]) + (aa[2]-aa[3]);
    v2f T6 = (aa[0]+aa[1]) - (aa[2]+aa[3]);
    v2f S  = (aa[0]+aa[1]) + (aa[2]+aa[3]);
    float q8 = T8.x + T8.y;
    float q7 = T7.x + T7.y;
    float q6 = T6.x + T6.y;
    float q9 = S.x - S.y;
    float P  = S.x + S.y;

    float v = P;
    { float pt = xor1f (v,lane); v = h5 ? (pt - v) : (pt + v); }
    { float pt = xor2f (v,lane); v = h4 ? (pt - v) : (pt + v); }
    { float pt = xor4f (v,lane); v = h3 ? (pt - v) : (pt + v); }
    { float pt = xor8f (v,lane); v = h2 ? (pt - v) : (pt + v); }
    { float pt = xor16f(v,lane); v = h1 ? (pt - v) : (pt + v); }
    { float pt = xor32f(v,lane); v = h0 ? (pt - v) : (pt + v); }

    q6 = dsum(q6); q7 = dsum(q7); q8 = dsum(q8); q9 = dsum(q9);

    if (lane==32) dst[0]=v;
    if (lane==16) dst[1]=v;
    if (lane== 8) dst[2]=v;
    if (lane== 4) dst[3]=v;
    if (lane== 2) dst[4]=v;
    if (lane== 1) dst[5]=v;
    if (lane==63){ dst[6]=q6; dst[7]=q7; dst[8]=q8; dst[9]=q9; }
  }

  // ---- outs[1]=<X>, outs[2]=outs[3]=-<Y>, direct from psi0
#define XYC(PFN,HW,W) { \
    v2f U=vs(0.f), V=vs(0.f); \
    _Pragma("unroll") \
    for (int p=0;p<8;++p) { \
      v2f PR = PFN(R[p],lane); \
      v2f PI = PFN(I[p],lane); \
      U += R[p]*PR + I[p]*PI; \
      V += I[p]*PR - R[p]*PI; \
    } \
    float u = U.x + U.y; \
    float vv = V.x + V.y; \
    vv = (HW) ? vv : -vv; \
    u = dsum(u); vv = dsum(vv); \
    if (lane==63){ dst[10+(W)]=u; dst[20+(W)]=vv; dst[30+(W)]=vv; } \
  }
  XYC(xor32v,h0,0) XYC(xor16v,h1,1) XYC(xor8v,h2,2)
  XYC(xor4v ,h3,3) XYC(xor2v ,h4,4) XYC(xor1v,h5,5)
#undef XYC

#define XYL(PM,W) { \
    v2f U=vs(0.f), V=vs(0.f); \
    _Pragma("unroll") \
    for (int p=0;p<8;++p) if (!(p&(PM))) { \
      const int q=p|(PM); \
      U += R[p]*R[q] + I[p]*I[q]; \
      V += I[p]*R[q] - R[p]*I[q]; \
    } \
    float u = U.x + U.y; \
    float vv = V.x + V.y; \
    u = dsum(u); vv = dsum(vv); \
    if (lane==63){ dst[10+(W)]=2.f*u; float y=-2.f*vv; dst[20+(W)]=y; dst[30+(W)]=y; } \
  }
  XYL(4,6) XYL(2,7) XYL(1,8)
#undef XYL

  {
    float u=0.f, vv=0.f;
#pragma unroll
    for (int p=0;p<8;++p) {
      u  = fmaf(R[p].x, R[p].y, u);  u  = fmaf(I[p].x, I[p].y, u);
      vv = fmaf(I[p].x, R[p].y, vv); vv = fmaf(-R[p].x, I[p].y, vv);
    }
    u = dsum(u); vv = dsum(vv);
    if (lane==63){ dst[19]=2.f*u; float y=-2.f*vv; dst[29]=y; dst[39]=y; }
  }

  // ---- fused epilogue: x2 = relu(x@clin^T+b); out = [x1,x2]@lin^T + b
  __syncthreads();
  if (tix < 160) {
    const int sl = tix/40, f = tix - sl*40;
    const float4* cw = (const float4*)(clin_w + f*40);
    float acc = clin_b[f];
#pragma unroll
    for (int q = 0; q < 10; ++q) {
      float4 v = cw[q];
      acc = fmaf(v.x, xs[sl][4*q+0], acc);
      acc = fmaf(v.y, xs[sl][4*q+1], acc);
      acc = fmaf(v.z, xs[sl][4*q+2], acc);
      acc = fmaf(v.w, xs[sl][4*q+3], acc);
    }
    x2s[sl][f] = fmaxf(acc, 0.f);
  }
  __syncthreads();
  if (tix < 160) {
    const int sl = tix/40, f = tix - sl*40;
    const float4* lw = (const float4*)(lin_w + f*80);
    float o = lin_b[f];
#pragma unroll
    for (int q = 0; q < 10; ++q) {
      float4 v = lw[q];
      o = fmaf(v.x, x1s[sl][4*q+0], o);
      o = fmaf(v.y, x1s[sl][4*q+1], o);
      o = fmaf(v.z, x1s[sl][4*q+2], o);
      o = fmaf(v.w, x1s[sl][4*q+3], o);
    }
#pragma unroll
    for (int q = 10; q < 20; ++q) {
      float4 v = lw[q];
      o = fmaf(v.x, x2s[sl][4*(q-10)+0], o);
      o = fmaf(v.y, x2s[sl][4*(q-10)+1], o);
      o = fmaf(v.z, x2s[sl][4*(q-10)+2], o);
      o = fmaf(v.w, x2s[sl][4*(q-10)+3], o);
    }
    out[blockIdx.x*160 + tix] = o;
  }
}

// ---------------- launch ---------------------------------------------------
extern "C" void kernel_launch(void* const* d_in, const int* in_sizes, int n_in,
                              void* d_out, int out_size, void* d_ws, size_t ws_size,
                              hipStream_t stream)
{
  const float* x      = (const float*)d_in[0];
  const float* qlin_w = (const float*)d_in[1];
  const float* qlin_b = (const float*)d_in[2];
  const float* bn_g   = (const float*)d_in[3];
  const float* bn_b   = (const float*)d_in[4];
  const float* clin_w = (const float*)d_in[5];
  const float* clin_b = (const float*)d_in[6];
  const float* lin_w  = (const float*)d_in[7];
  const float* lin_b  = (const float*)d_in[8];
  const float* rz1    = (const float*)d_in[9];
  const float* ry1    = (const float*)d_in[10];
  const float* rz2    = (const float*)d_in[11];

  float* ps  = (float*)d_ws;     // 640 floats of partials
  float* out = (float*)d_out;

  hipLaunchKernelGGL(k_pre, dim3(320),  dim3(256), 0, stream, x, qlin_w, qlin_b, ps);
  hipLaunchKernelGGL(k_qnn, dim3(2048), dim3(256), 0, stream,
                     x, qlin_w, qlin_b, ps, bn_g, bn_b, rz1, ry1, rz2,
                     clin_w, clin_b, lin_w, lin_b, out);
}